// Round 1
// baseline (477.285 us; speedup 1.0000x reference)
//
#include <hip/hip_runtime.h>
#include <stdint.h>

#define BB   16
#define NN   65536
#define FF   32
#define KSEL 16384
#define SEG  32
#define EPSF 1e-10f

// ---- workspace layout (uint32 element offsets) ----
// total ~19.5 MB
#define WS_MIN   0
#define WS_PART  256                        // [SEG][256][512] partial histograms
#define WS_HIST  (WS_PART + SEG*256*512)    // [256][512] reduced histogram (bin-major, coalesced by col)
#define WS_PREF  (WS_HIST + 256*512)        // [512] resolved prefix bits
#define WS_REM   (WS_PREF + 512)            // [512] remaining rank
#define WS_TKEY  (WS_REM + 512)             // [512] final threshold key
#define WS_TIE   (WS_TKEY + 512)            // [512] # of equal-key elements to take (lowest idx first)
#define WS_FLAG  (WS_TIE + 512)             // [512] 1 if take ALL equals (common case)
#define WS_EQC   (WS_FLAG + 512)            // [512] equal-list counters
#define WS_EQL   (WS_EQC + 512)             // [512][1024] equal-index lists

__device__ __forceinline__ uint32_t fkey(float s) {
    uint32_t u = __float_as_uint(s);
    return (u & 0x80000000u) ? ~u : (u | 0x80000000u);
}

// ---- 1) global min(|x|) ----
__global__ __launch_bounds__(256) void kmin(const float4* __restrict__ x, uint32_t* __restrict__ ws) {
    __shared__ uint32_t red[256];
    uint32_t m = 0xFFFFFFFFu;
    const int tot = BB * NN * FF / 4;
    for (int i = blockIdx.x * 256 + threadIdx.x; i < tot; i += gridDim.x * 256) {
        float4 v = x[i];
        uint32_t a0 = __float_as_uint(v.x) & 0x7FFFFFFFu;
        uint32_t a1 = __float_as_uint(v.y) & 0x7FFFFFFFu;
        uint32_t a2 = __float_as_uint(v.z) & 0x7FFFFFFFu;
        uint32_t a3 = __float_as_uint(v.w) & 0x7FFFFFFFu;
        uint32_t a01 = a0 < a1 ? a0 : a1;
        uint32_t a23 = a2 < a3 ? a2 : a3;
        uint32_t a = a01 < a23 ? a01 : a23;
        m = a < m ? a : m;
    }
    red[threadIdx.x] = m;
    __syncthreads();
    for (int off = 128; off > 0; off >>= 1) {
        if (threadIdx.x < off) {
            uint32_t o = red[threadIdx.x + off];
            if (o < red[threadIdx.x]) red[threadIdx.x] = o;
        }
        __syncthreads();
    }
    if (threadIdx.x == 0) atomicMin(&ws[WS_MIN], red[0]);
}

// ---- 2) per-pass histogram: one WG = (batch b, segment s of 2048 rows), all 32 features ----
template <int PASS>
__global__ __launch_bounds__(256) void khist(const float* __restrict__ xf, const float* __restrict__ mask,
                                             uint32_t* __restrict__ ws) {
    __shared__ uint32_t lh[256 * 33];   // [bin][f], stride 33 to break bank patterns
    __shared__ uint32_t lpref[32];
    __shared__ float lmin;
    const int b = blockIdx.x >> 5;
    const int s = blockIdx.x & 31;
    const int tid = threadIdx.x;
    for (int i = tid; i < 256 * 33; i += 256) lh[i] = 0;
    if (tid < 32) lpref[tid] = (PASS > 0) ? ws[WS_PREF + b * 32 + tid] : 0u;
    if (tid == 0) lmin = __uint_as_float(ws[WS_MIN]);
    __syncthreads();
    const float4* x4 = (const float4*)xf + (size_t)b * (NN * FF / 4) + (size_t)s * 16384;
    const float* mb = mask + (size_t)b * NN + s * 2048;
    const float mn = lmin;
    for (int i = 0; i < 64; ++i) {
        int e = i * 256 + tid;          // float4 index in segment [0,16384)
        float4 v = x4[e];
        int n = e >> 3;
        float mk = mb[n];
        int fb = (e & 7) * 4;
        float vv[4] = {v.x, v.y, v.z, v.w};
#pragma unroll
        for (int j = 0; j < 4; ++j) {
            float sv = ((vv[j] + mn) + EPSF) * mk;
            uint32_t key = fkey(sv);
            bool match = true;
            if (PASS > 0) match = ((key >> (32 - 8 * PASS)) == lpref[fb + j]);
            if (match) {
                uint32_t bin = (key >> (24 - 8 * PASS)) & 255u;
                atomicAdd(&lh[bin * 33 + fb + j], 1u);
            }
        }
    }
    __syncthreads();
    uint32_t* part = ws + WS_PART;
    for (int k = tid; k < 8192; k += 256) {
        int f = k & 31, bin = k >> 5;
        part[((size_t)s * 256 + bin) * 512 + b * 32 + f] = lh[bin * 33 + f];
    }
}

// ---- 3) reduce partials: hist[bin][col] = sum_s part[s][bin][col] ----
__global__ __launch_bounds__(256) void kreduce(uint32_t* __restrict__ ws) {
    const int bin = blockIdx.x;
    const uint32_t* part = ws + WS_PART;
    uint32_t* hist = ws + WS_HIST;
    for (int col = threadIdx.x; col < 512; col += 256) {
        uint32_t sum = 0;
#pragma unroll 4
        for (int s = 0; s < SEG; ++s) sum += part[((size_t)s * 256 + bin) * 512 + col];
        hist[bin * 512 + col] = sum;
    }
}

// ---- 4) per-column resolve: find bucket containing the r-th largest ----
template <int PASS>
__global__ void kresolve(uint32_t* __restrict__ ws) {
    const int col = blockIdx.x * 128 + threadIdx.x;
    if (col >= 512) return;
    const uint32_t* hist = ws + WS_HIST;
    uint32_t r = (PASS == 0) ? (uint32_t)KSEL : ws[WS_REM + col];
    uint32_t pref = (PASS == 0) ? 0u : ws[WS_PREF + col];
    uint32_t cum = 0, v = 0, hv = 0;
    for (int bin = 255; bin >= 0; --bin) {
        uint32_t h = hist[bin * 512 + col];
        if (cum + h >= r) { v = (uint32_t)bin; hv = h; break; }
        cum += h;
    }
    pref = (pref << 8) | v;
    r -= cum;
    if (PASS == 3) {
        ws[WS_TKEY + col] = pref;         // exact f32 key of K-th largest
        ws[WS_TIE + col] = r;             // how many equals to take
        ws[WS_FLAG + col] = (r == hv) ? 1u : 0u;  // take all equals?
        ws[WS_EQC + col] = 0u;
    } else {
        ws[WS_PREF + col] = pref;
        ws[WS_REM + col] = r;
    }
}

// ---- 5) mark: write updated (B,N) and masked (B,N,F); collect rare boundary ties ----
__global__ __launch_bounds__(256) void kmark(const float* __restrict__ xf, const float* __restrict__ mask,
                                             uint32_t* __restrict__ ws, float* __restrict__ upd,
                                             float* __restrict__ omask) {
    __shared__ uint32_t lT[32], lF[32];
    __shared__ float lmin;
    const int b = blockIdx.x >> 11;     // 2048 blocks per batch
    const int blk = blockIdx.x & 2047;
    const int tid = threadIdx.x;
    if (tid < 32) { lT[tid] = ws[WS_TKEY + b * 32 + tid]; lF[tid] = ws[WS_FLAG + b * 32 + tid]; }
    if (tid == 0) lmin = __uint_as_float(ws[WS_MIN]);
    __syncthreads();
    const int e = blk * 256 + tid;      // float4 index within batch [0, 524288)
    const float4 v = ((const float4*)xf)[(size_t)b * 524288 + e];
    const int n = e >> 3;
    const int fb = (e & 7) * 4;
    const float mk = mask[(size_t)b * NN + n];
    const float mn = lmin;
    float vv[4] = {v.x, v.y, v.z, v.w};
    bool sel = false;
#pragma unroll
    for (int j = 0; j < 4; ++j) {
        float sv = ((vv[j] + mn) + EPSF) * mk;
        uint32_t key = fkey(sv);
        uint32_t T = lT[fb + j];
        if (key > T) {
            sel = true;
        } else if (key == T) {
            if (lF[fb + j]) {
                sel = true;
            } else {
                uint32_t col = (uint32_t)(b * 32 + fb + j);
                uint32_t idx = atomicAdd(&ws[WS_EQC + col], 1u);
                if (idx < 1024u) ws[WS_EQL + (size_t)col * 1024 + idx] = (uint32_t)n;
            }
        }
    }
    unsigned long long bal = __ballot(sel);
    int lane = tid & 63;
    uint32_t grp = (uint32_t)(bal >> (lane & 56)) & 0xFFu;   // 8 lanes = 32 features of this n
    float u1 = grp ? 1.0f : 0.0f;
    float4 o;
    o.x = vv[0] * u1; o.y = vv[1] * u1; o.z = vv[2] * u1; o.w = vv[3] * u1;
    ((float4*)omask)[(size_t)b * 524288 + e] = o;
    if ((tid & 7) == 0) upd[(size_t)b * NN + n] = u1;
}

// ---- 6) fixup rare boundary ties: take lowest-index equals ----
__global__ void kfix(const float* __restrict__ xf, uint32_t* __restrict__ ws,
                     float* __restrict__ upd, float* __restrict__ omask) {
    const int col = blockIdx.x * 128 + threadIdx.x;
    if (col >= 512) return;
    if (ws[WS_FLAG + col]) return;
    uint32_t take = ws[WS_TIE + col];
    uint32_t cnt = ws[WS_EQC + col];
    if (cnt > 1024u) cnt = 1024u;
    if (take > cnt) take = cnt;
    uint32_t* lst = ws + WS_EQL + (size_t)col * 1024;
    const int b = col >> 5;
    for (uint32_t t = 0; t < take; ++t) {
        uint32_t best = 0xFFFFFFFFu, bi = 0;
        for (uint32_t i = 0; i < cnt; ++i) {
            uint32_t val = lst[i];
            if (val < best) { best = val; bi = i; }
        }
        lst[bi] = 0xFFFFFFFFu;
        uint32_t n = best;
        upd[(size_t)b * NN + n] = 1.0f;
        const float* xr = xf + ((size_t)b * NN + n) * FF;
        float* orow = omask + ((size_t)b * NN + n) * FF;
        for (int f = 0; f < FF; ++f) orow[f] = xr[f];
    }
}

extern "C" void kernel_launch(void* const* d_in, const int* in_sizes, int n_in,
                              void* d_out, int out_size, void* d_ws, size_t ws_size,
                              hipStream_t stream) {
    const float* x = (const float*)d_in[0];
    const float* mask = (const float*)d_in[1];
    float* upd = (float*)d_out;                       // (B,N,1)
    float* omask = (float*)d_out + (size_t)BB * NN;   // (B,N,F)
    uint32_t* ws = (uint32_t*)d_ws;

    hipMemsetAsync(d_ws, 0xFF, 4, stream);            // init min to +inf-ish
    kmin<<<2048, 256, 0, stream>>>((const float4*)x, ws);

    khist<0><<<BB * SEG, 256, 0, stream>>>(x, mask, ws);
    kreduce<<<256, 256, 0, stream>>>(ws);
    kresolve<0><<<4, 128, 0, stream>>>(ws);

    khist<1><<<BB * SEG, 256, 0, stream>>>(x, mask, ws);
    kreduce<<<256, 256, 0, stream>>>(ws);
    kresolve<1><<<4, 128, 0, stream>>>(ws);

    khist<2><<<BB * SEG, 256, 0, stream>>>(x, mask, ws);
    kreduce<<<256, 256, 0, stream>>>(ws);
    kresolve<2><<<4, 128, 0, stream>>>(ws);

    khist<3><<<BB * SEG, 256, 0, stream>>>(x, mask, ws);
    kreduce<<<256, 256, 0, stream>>>(ws);
    kresolve<3><<<4, 128, 0, stream>>>(ws);

    kmark<<<BB * 2048, 256, 0, stream>>>(x, mask, ws, upd, omask);
    kfix<<<4, 128, 0, stream>>>(x, ws, upd, omask);
}